// Round 1
// 410.962 us; speedup vs baseline: 1.0466x; 1.0466x over previous
//
#include <hip/hip_runtime.h>

#define NN     2048
#define DIM    512
#define NH     8
#define HD     64
#define NE     32768
#define EPAD   32832
#define CHUNKS 8
#define CHSZ   (NN/CHUNKS)      /* 256 keys per chunk */
#define NJT    (CHSZ/64)        /* 4 key-tiles of 64 per chunk */
#define LOG2E  1.4426950408889634f

typedef __attribute__((ext_vector_type(8))) short bf16x8;
typedef __attribute__((ext_vector_type(4))) float f32x4;

#define MFMA(a,b,c) __builtin_amdgcn_mfma_f32_16x16x32_bf16((a),(b),(c),0,0,0)

__device__ __forceinline__ float bf2f(unsigned int u16){
  union { unsigned int i; float f; } v; v.i = u16 << 16; return v.f;
}
__device__ __forceinline__ unsigned short f2bf(float f){
  union { float ff; unsigned int i; } v; v.ff = f;
  return (unsigned short)((v.i + 0x7fffu + ((v.i >> 16) & 1u)) >> 16);
}

// ------- fp32 -> bf16 staging: node_feat -> Xb, edge_feat -> pEF (pad rows NE..EPAD-1 = 0),
// ------- edge_weight -> pEW (64 rows, rows 40..63 = 0). One 8-elem group per thread.
__global__ __launch_bounds__(256) void cvt_k(
    const float* __restrict__ X, const float* __restrict__ ef, const float* __restrict__ ew,
    unsigned short* __restrict__ Xb, unsigned short* __restrict__ pEF, unsigned short* __restrict__ pEW)
{
  long g = (long)blockIdx.x*256 + threadIdx.x;   // 8-element group index
  const long GX = (long)NN*DIM/8;                // 131072 groups
  const long GE = (long)EPAD*8;                  // 262656 groups
  const float* src; unsigned short* dst; long off, lim8;
  if (g < GX){ src = X;  dst = Xb;  off = g;        lim8 = GX; }
  else if (g < GX+GE){ src = ef; dst = pEF; off = g-GX; lim8 = (long)NE*8; }
  else { off = g-GX-GE; if (off >= 512) return; src = ew; dst = pEW; lim8 = 320; }
  unsigned short o[8];
  if (off < lim8){
    #pragma unroll
    for (int i=0;i<8;i++) o[i] = f2bf(src[off*8+i]);
  } else {
    #pragma unroll
    for (int i=0;i<8;i++) o[i] = 0;
  }
  *(uint4*)(dst + off*8) = *(const uint4*)o;
}

// ---------------- transpose + convert four 512x512 fp32 weight matrices -> bf16 ----------------
__global__ __launch_bounds__(256) void transpose512(
    const float* __restrict__ a0, const float* __restrict__ a1,
    const float* __restrict__ a2, const float* __restrict__ a3,
    unsigned short* __restrict__ out)
{
  __shared__ unsigned short tile[32][33];
  const float* src = blockIdx.z==0 ? a0 : blockIdx.z==1 ? a1 : blockIdx.z==2 ? a2 : a3;
  unsigned short* dst = out + (size_t)blockIdx.z*DIM*DIM;
  int bx = blockIdx.x*32, by = blockIdx.y*32;
  int tx = threadIdx.x, ty = threadIdx.y;
  #pragma unroll
  for (int i=0;i<32;i+=8) tile[ty+i][tx] = f2bf(src[(size_t)(by+ty+i)*DIM + bx+tx]);
  __syncthreads();
  #pragma unroll
  for (int i=0;i<32;i+=8) dst[(size_t)(bx+ty+i)*DIM + by+tx] = tile[tx][ty+i];
}

// ---------------- C[M][N] = A1[M][K] * A2[N][K]^T + bias(fp32) ----------------
// Wave tile 16x32 (acc[2]) instead of 16x64: these GEMMs are small (1 GF) and were
// running at 1 wave/SIMD -> latency-exposed. 2x the waves at 1.5 loads/MFMA.
__global__ __launch_bounds__(256) void gemm_bt(
    const unsigned short* __restrict__ A1, const unsigned short* __restrict__ A2,
    const float* __restrict__ bias, unsigned short* __restrict__ C, float* __restrict__ Cf,
    int M, int N, int K, int bias_row)
{
  int lane = threadIdx.x & 63, w = threadIdx.x >> 6;
  int quad = lane >> 4, low = lane & 15;
  int m0 = blockIdx.y*64 + w*16;
  int n0 = blockIdx.x*32;
  f32x4 acc[2];
  acc[0] = (f32x4){0.f,0.f,0.f,0.f};
  acc[1] = (f32x4){0.f,0.f,0.f,0.f};
  for (int k0=0; k0<K; k0+=32){
    bf16x8 a = *(const bf16x8*)(A1 + (size_t)(m0+low)*K + k0 + quad*8);
    #pragma unroll
    for (int t=0;t<2;t++){
      bf16x8 b = *(const bf16x8*)(A2 + (size_t)(n0+16*t+low)*K + k0 + quad*8);
      acc[t] = MFMA(a, b, acc[t]);
    }
  }
  #pragma unroll
  for (int t=0;t<2;t++){
    #pragma unroll
    for (int r=0;r<4;r++){
      int row = m0 + quad*4 + r;
      int col = n0 + 16*t + low;
      float v = acc[t][r];
      if (bias) v += bias[bias_row ? row : col];
      if (Cf) Cf[(size_t)row*N + col] = v;
      else    C [(size_t)row*N + col] = f2bf(v);
    }
  }
}

// ---------------- fused attention ----------------
// block = 512 threads = 8 waves, wave h owns head h.
// blockIdx.x = q-tile (16 queries), blockIdx.y = m-chunk (CHSZ keys = NJT tiles of 64).
// Softmax is over HEADS per (q,m) pair (reference uses axis=-1 on (n,m,h)!).
// Pipelined: next tile's dist/sp/mask indices prefetched into registers; the
// sp->T2 dependent gather chain is computed into registers BEFORE the barrier
// that frees LDS, overlapping the prior tile's PV phase.
__global__ __launch_bounds__(512) void attn_k(
    const unsigned short* __restrict__ Qb, const unsigned short* __restrict__ Kb,
    const unsigned short* __restrict__ Vt, const unsigned short* __restrict__ T2,
    const float* __restrict__ spb, const int* __restrict__ dist,
    const int* __restrict__ sp, const int* __restrict__ maskp,
    float* __restrict__ partO)
{
  __shared__ __attribute__((aligned(16))) float sld[NH][16][68];  // stride 68: 2-way aliasing only
  __shared__ float sptab[48];
  int tid = threadIdx.x;
  int lane = tid & 63, h = tid >> 6;
  int quad = lane >> 4, low = lane & 15;
  int q0 = blockIdx.x * 16;
  int chunk = blockIdx.y;
  if (tid < 48) sptab[tid] = spb[tid];

  bf16x8 aq[2];
  #pragma unroll
  for (int s=0;s<2;s++)
    aq[s] = *(const bf16x8*)(Qb + (size_t)(q0+low)*DIM + h*HD + s*32 + quad*8);

  f32x4 accO[4];
  #pragma unroll
  for (int t=0;t<4;t++) accO[t] = (f32x4){0.f,0.f,0.f,0.f};

  // ---- prefetch registers for the bias-gather indices of the NEXT key-tile ----
  int pd[2], pm[2], pe[2][5];
  #pragma unroll
  for (int it=0; it<2; ++it){
    int p = tid + it*512;
    int qq = p >> 6, mm = p & 63;
    long pix = (long)(q0+qq)*NN + (chunk*CHSZ + mm);
    pd[it] = dist[pix]; pm[it] = maskp[pix];
    #pragma unroll
    for (int l=0;l<5;l++) pe[it][l] = sp[pix*5 + l];
  }
  __syncthreads();   // sptab visible to all waves

  for (int jt=0; jt<NJT; ++jt){
    int m0 = chunk*CHSZ + jt*64;

    // ---- phase A-regs: bias(q,m,h) into registers from prefetched indices ----
    // (no LDS touched: overlaps prior iteration's phase-D + barrier wait)
    float bb[2][8];
    int mk[2];
    #pragma unroll
    for (int it=0; it<2; ++it){
      mk[it] = pm[it];
      int dd = pd[it];
      dd = dd < 0 ? 0 : (dd > 5 ? 5 : dd);
      #pragma unroll
      for (int x=0;x<8;x++) bb[it][x] = sptab[dd*8 + x];
      #pragma unroll
      for (int l=0;l<5;l++){
        int e = pe[it][l];
        if ((unsigned)e > (unsigned)NE) e = NE;
        uint4 tv = *(const uint4*)(T2 + (size_t)e*64 + l*8);
        bb[it][0] += bf2f(tv.x & 0xffffu); bb[it][1] += bf2f(tv.x >> 16);
        bb[it][2] += bf2f(tv.y & 0xffffu); bb[it][3] += bf2f(tv.y >> 16);
        bb[it][4] += bf2f(tv.z & 0xffffu); bb[it][5] += bf2f(tv.z >> 16);
        bb[it][6] += bf2f(tv.w & 0xffffu); bb[it][7] += bf2f(tv.w >> 16);
      }
    }

    __syncthreads();   // prior iteration's phase-D LDS readers done

    // ---- phase A-write: registers -> LDS ----
    #pragma unroll
    for (int it=0; it<2; ++it){
      int p = tid + it*512;
      int qq = p >> 6, mm = p & 63;
      #pragma unroll
      for (int x=0;x<8;x++) sld[x][qq][mm] = mk[it] ? -1e30f : bb[it][x];
    }

    // ---- issue next tile's index loads (consumed 1 iteration later) ----
    if (jt+1 < NJT){
      #pragma unroll
      for (int it=0; it<2; ++it){
        int p = tid + it*512;
        int qq = p >> 6, mm = p & 63;
        long pix = (long)(q0+qq)*NN + (m0 + 64 + mm);
        pd[it] = dist[pix]; pm[it] = maskp[pix];
        #pragma unroll
        for (int l=0;l<5;l++) pe[it][l] = sp[pix*5 + l];
      }
    }
    __syncthreads();

    // ---- phase B (wave h): S = Q K^T * 0.125 + bias, write back into own slice ----
    f32x4 S[4];
    #pragma unroll
    for (int t=0;t<4;t++) S[t] = (f32x4){0.f,0.f,0.f,0.f};
    #pragma unroll
    for (int s=0;s<2;s++){
      #pragma unroll
      for (int t=0;t<4;t++){
        bf16x8 bk = *(const bf16x8*)(Kb + (size_t)(m0+16*t+low)*DIM + h*HD + s*32 + quad*8);
        S[t] = MFMA(aq[s], bk, S[t]);
      }
    }
    #pragma unroll
    for (int t=0;t<4;t++){
      #pragma unroll
      for (int r=0;r<4;r++){
        float* slot = &sld[h][quad*4+r][low+16*t];
        *slot = S[t][r]*0.125f + *slot;
      }
    }
    __syncthreads();

    // ---- phase C (cooperative): softmax over the 8 heads per (q,m) pair ----
    #pragma unroll
    for (int it=0; it<2; ++it){
      int p = tid + it*512;
      int qq = p >> 6, mm = p & 63;
      float s0[8];
      #pragma unroll
      for (int x=0;x<8;x++) s0[x] = sld[x][qq][mm];
      float mx = s0[0];
      #pragma unroll
      for (int x=1;x<8;x++) mx = fmaxf(mx, s0[x]);
      float sum = 0.f;
      #pragma unroll
      for (int x=0;x<8;x++){ s0[x] = exp2f((s0[x]-mx)*LOG2E); sum += s0[x]; }
      float inv = (mx < -1e29f) ? 0.f : 1.f/sum;   // fully-masked pair -> zero weights
      #pragma unroll
      for (int x=0;x<8;x++) sld[x][qq][mm] = s0[x]*inv;
    }
    __syncthreads();

    // ---- phase D (wave h): O += P V ----
    bf16x8 ap[2];
    #pragma unroll
    for (int s=0;s<2;s++){
      const float* pp = &sld[h][low][s*32 + quad*8];
      float4 x0 = *(const float4*)pp;
      float4 x1 = *(const float4*)(pp + 4);
      bf16x8 a;
      a[0]=(short)f2bf(x0.x); a[1]=(short)f2bf(x0.y); a[2]=(short)f2bf(x0.z); a[3]=(short)f2bf(x0.w);
      a[4]=(short)f2bf(x1.x); a[5]=(short)f2bf(x1.y); a[6]=(short)f2bf(x1.z); a[7]=(short)f2bf(x1.w);
      ap[s] = a;
    }
    #pragma unroll
    for (int s=0;s<2;s++){
      #pragma unroll
      for (int t=0;t<4;t++){
        bf16x8 bv = *(const bf16x8*)(Vt + (size_t)(h*HD + 16*t + low)*NN + m0 + s*32 + quad*8);
        accO[t] = MFMA(ap[s], bv, accO[t]);
      }
    }
  }

  // ---- epilogue: per-chunk partial O (plain sum over m; no softmax state) ----
  #pragma unroll
  for (int t=0;t<4;t++){
    #pragma unroll
    for (int r=0;r<4;r++){
      int q = quad*4 + r;
      partO[(((size_t)chunk*NN + q0 + q)*NH + h)*HD + 16*t + low] = accO[t][r];
    }
  }
}

// ---------------- sum the CHUNKS partial O's, emit bf16 ----------------
__global__ __launch_bounds__(512) void merge_k(const float* __restrict__ partO,
                                               unsigned short* __restrict__ Obf)
{
  size_t idx = (size_t)blockIdx.x*512 + threadIdx.x;   // q*512 + h*64 + d
  float s = 0.f;
  #pragma unroll
  for (int c=0;c<CHUNKS;c++) s += partO[(size_t)c*NN*DIM + idx];
  Obf[idx] = f2bf(s);
}

extern "C" void kernel_launch(void* const* d_in, const int* in_sizes, int n_in,
                              void* d_out, int out_size, void* d_ws, size_t ws_size,
                              hipStream_t stream)
{
  const float* X    = (const float*)d_in[0];
  const int*  dist  = (const int*)d_in[3];
  const int*  sp    = (const int*)d_in[4];
  const float* ef   = (const float*)d_in[5];
  const int*  maskp = (const int*)d_in[6];
  const float* WQ   = (const float*)d_in[7];
  const float* bQ   = (const float*)d_in[8];
  const float* WK   = (const float*)d_in[9];
  const float* bK   = (const float*)d_in[10];
  const float* WV   = (const float*)d_in[11];
  const float* bV   = (const float*)d_in[12];
  const float* WO   = (const float*)d_in[13];
  const float* bO   = (const float*)d_in[14];
  const float* spb  = (const float*)d_in[15];
  const float* ew   = (const float*)d_in[16];

  char* ws = (char*)d_ws;
  unsigned short* Wt   = (unsigned short*)(ws + 0);            // 4 x 512x512 bf16 (Q,K,V,O transposed)
  unsigned short* Xb   = (unsigned short*)(ws + 2097152);      // 2048x512 bf16 node_feat
  unsigned short* Qb   = (unsigned short*)(ws + 4194304);      // 2048x512 bf16
  unsigned short* Kb   = (unsigned short*)(ws + 6291456);      // 2048x512 bf16
  unsigned short* Vtb  = (unsigned short*)(ws + 8388608);      // 512x2048 bf16 (transposed V)
  unsigned short* pEF  = (unsigned short*)(ws + 10485760);     // EPAD x 64 bf16
  unsigned short* pEW  = (unsigned short*)(ws + 14688256);     // 64 x 64 bf16
  unsigned short* T2   = (unsigned short*)(ws + 14696448);     // EPAD x 64 bf16: T2[e][l*8+h]
  unsigned short* Obf  = (unsigned short*)(ws + 18898944);     // 2048x512 bf16
  float*          pO   = (float*)(ws + 20996096);              // CHUNKS x 2048x512 f32 (33.5 MB; ws total ~55 MB)

  cvt_k<<<dim3(1540), dim3(256), 0, stream>>>(X, ef, ew, Xb, pEF, pEW);
  transpose512<<<dim3(16,16,4), dim3(32,8), 0, stream>>>(WQ, WK, WV, WO, Wt);
  gemm_bt<<<dim3(2,513),  dim3(256), 0, stream>>>(pEF, pEW, (const float*)nullptr, T2, (float*)nullptr, EPAD, 64, 64, 0);
  gemm_bt<<<dim3(16,32),  dim3(256), 0, stream>>>(Xb,  Wt,          bQ, Qb,  (float*)nullptr, NN, DIM, DIM, 0);
  gemm_bt<<<dim3(16,32),  dim3(256), 0, stream>>>(Xb,  Wt + 262144, bK, Kb,  (float*)nullptr, NN, DIM, DIM, 0);
  gemm_bt<<<dim3(64,8),   dim3(256), 0, stream>>>(Wt + 524288, Xb,  bV, Vtb, (float*)nullptr, DIM, NN, DIM, 1);
  attn_k<<<dim3(128,CHUNKS), dim3(512), 0, stream>>>(Qb, Kb, Vtb, T2, spb, dist, sp, maskp, pO);
  merge_k<<<dim3(2048), dim3(512), 0, stream>>>(pO, Obf);
  gemm_bt<<<dim3(16,32), dim3(256), 0, stream>>>(Obf, Wt + 786432, bO, (unsigned short*)nullptr, (float*)d_out, NN, DIM, DIM, 0);
}